// Round 5
// baseline (204.551 us; speedup 1.0000x reference)
//
#include <hip/hip_runtime.h>
#include <math.h>

#define NBATCH 32
#define S      49152
#define NF     24          // frames (2048 samples each)
#define NB     16          // biquads
#define NP     8           // fused biquad PAIRS  (R14: combine rounds 16 -> 8)
#define NBLK   4           // blocks per batch (R9-proven best)
#define CHUNK  16          // samples per thread (R9-proven; 32 spilled in R13)
#define NCH    768         // threads per block
#define NWAVE  12          // waves per block
// R14: biquad-PAIR fusion. Evidence R9-R13: time pinned ~74us whenever no
// scratch; insensitive to barriers/spin topology, payload, occupancy; R11
// showed ~15x amplification of per-ROUND serial additions; R13's CHUNK=32
// spilled (WRITE 7.4->77MB) and was uninterpretable. The invariant of all
// 74us variants is 16 combine rounds at ~4.6k cy wall each. R14 halves the
// round count: biquads (2p,2p+1) fuse into a 4-state section, state
// u=(j1,j2,k1,k2), u' = Tp u + bp x, Tp block-lower-triangular (3 2x2
// blocks; M12=0 is closed under powers/products). Wave-uniform-M KS, binexp
// distribute, R9's 2-barrier + wave-0 second level all carry over with 4-dim
// constants. 8 rounds, 16 barriers, 8 L2 handshakes. Payload +10%, KS ~30%
// heavier per round. Health check: WRITE_SIZE must stay ~7.4MB (no scratch).

__device__ __forceinline__ float clampf(float x, float lo, float hi) {
    return fminf(fmaxf(x, lo), hi);
}

// 16 named scalar signal registers (SSA-guaranteed; R1-R4: arrays spill).
#define FOREACH_S(OP) \
    OP(s00) OP(s01) OP(s02) OP(s03) OP(s04) OP(s05) OP(s06) OP(s07) \
    OP(s08) OP(s09) OP(s10) OP(s11) OP(s12) OP(s13) OP(s14) OP(s15)

#define DECL_S(x) float x;

// Phase A step: state only (zero-output pass), fused pair.
#define STEPA2(x) { \
    const float y1_  = fmaf(c0a, j1, fmaf(c1a, j2, c2a * (x))); \
    const float nj1_ = fmaf(t00a, j1, fmaf(t01a, j2, b0a * (x))); \
    const float nj2_ = fmaf(t10a, j1, fmaf(t11a, j2, b1a * (x))); \
    const float nk1_ = fmaf(t00b, k1, fmaf(t01b, k2, b0b * y1_)); \
    const float nk2_ = fmaf(t10b, k1, fmaf(t11b, k2, b1b * y1_)); \
    j1 = nj1_; j2 = nj2_; k1 = nk1_; k2 = nk2_; }

// Phase C step: output + state, in place.
#define STEPC2(x) { \
    const float y1_  = fmaf(c0a, j1, fmaf(c1a, j2, c2a * (x))); \
    const float y2_  = fmaf(c0b, k1, fmaf(c1b, k2, c2b * y1_)); \
    const float nj1_ = fmaf(t00a, j1, fmaf(t01a, j2, b0a * (x))); \
    const float nj2_ = fmaf(t10a, j1, fmaf(t11a, j2, b1a * (x))); \
    const float nk1_ = fmaf(t00b, k1, fmaf(t01b, k2, b0b * y1_)); \
    const float nk2_ = fmaf(t10b, k1, fmaf(t11b, k2, b1b * y1_)); \
    (x) = y2_; j1 = nj1_; j2 = nj2_; k1 = nk1_; k2 = nk2_; }

struct Aff { float t00, t01, t10, t11, b0, b1, c0, c1, c2; };

// per-biquad affine per-sample form: s' = T s + b*x ; y = c0*s1 + c1*s2 + c2*x
__device__ __forceinline__ Aff biquad_affine(int f, const float* P, int fr) {
    const float fn = P[(3 * f + 0) * NF + fr];
    const float gn = P[(3 * f + 1) * NF + fr];
    const float qn = P[(3 * f + 2) * NF + fr];

    float Q = __expf(-0.69314718f + qn * 3.4657359f);
    Q = clampf(Q, 0.1f, 100.0f);

    float lo, hi;
    int type;                        // 0 hp, 1 lp, 2 peak, 3 lowshelf, 4 highshelf
    if      (f == 0)  { lo = 20.0f;   hi = 500.0f;   type = 0; }
    else if (f == 15) { lo = 5000.0f; hi = 20000.0f; type = 1; }
    else if (f == 1)  { lo = 50.0f;   hi = 16000.0f; type = 3; }
    else if (f == 14) { lo = 50.0f;   hi = 16000.0f; type = 4; }
    else              { lo = 100.0f;  hi = 15000.0f; type = 2; }

    const float fc = __expf(__logf(lo) + fn * (__logf(hi) - __logf(lo)));
    float g_ = __tanf((float)M_PI * fc / 96000.0f);   // angle <= 0.655 rad
    g_ = clampf(g_, 1e-6f, 100.0f);
    const float gdb = -24.0f + 48.0f * gn;

    float a1, a2, a3, m0, m1, m2;
    if (type == 0 || type == 1) {
        const float k = 1.0f / Q;
        a1 = 1.0f / (1.0f + g_ * (g_ + k)); a2 = g_ * a1; a3 = g_ * a2;
        if (type == 0) { m0 = 1.0f; m1 = -k;   m2 = -1.0f; }
        else           { m0 = 0.0f; m1 = 0.0f; m2 = 1.0f;  }
    } else if (type == 2) {
        const float A = __expf(gdb * (2.30258509f / 40.0f));
        const float k = (gdb >= 0.0f) ? 1.0f / (Q * A) : A / Q;
        a1 = 1.0f / (1.0f + g_ * (g_ + k)); a2 = g_ * a1; a3 = g_ * a2;
        m0 = 1.0f; m1 = k * (A * A - 1.0f); m2 = 0.0f;
    } else {
        const float A  = __expf(gdb * (2.30258509f / 40.0f));
        const float sA = sqrtf(A);
        const float k  = 1.0f / Q;
        float gs;
        if (type == 3) gs = (gdb >= 0.0f) ? g_ / sA : g_ * sA;
        else           gs = (gdb >= 0.0f) ? g_ * sA : g_ / sA;
        a1 = 1.0f / (1.0f + gs * (gs + k)); a2 = gs * a1; a3 = gs * a2;
        if (type == 3) { m0 = 1.0f;  m1 = k * (A - 1.0f);      m2 = A * A - 1.0f; }
        else           { m0 = A * A; m1 = k * (1.0f - A) * A;  m2 = 1.0f - A * A; }
    }

    const float q2 = a2 * a2 + a3;
    Aff r;
    r.t00 = 2.0f * a1 - 1.0f;
    r.t01 = -2.0f * a2;
    r.t10 = 2.0f * a1 * a2;
    r.t11 = 1.0f - 2.0f * q2;
    r.b0  = 2.0f * a2;
    r.b1  = 2.0f * q2;
    r.c0  = a1 * (m1 + m2 * a2);
    r.c1  = m2 * (1.0f - q2) - m1 * a2;
    r.c2  = m0 + m1 * a2 + m2 * q2;
    return r;
}

__global__ __launch_bounds__(NCH, 3)
void biquad_chain_kernel(const float* __restrict__ audio,
                         const float* __restrict__ params,
                         float* __restrict__ out,
                         unsigned int* __restrict__ ws)
{
    __shared__ float sc[NP][NF][32];     // fused-pair coeffs, float4-aligned
    __shared__ float sgain[2][NF];       // [0]=in gain, [1]=out gain
    __shared__ float sagg[NWAVE][16];    // wave aggregate: M blocks (12) + c (4)
    __shared__ float sv[NWAVE][4];       // per-wave incoming 4-state

    const int t       = threadIdx.x;
    // XCD co-location swizzle (R8): all 4 quarters of a batch on one XCD.
    const int xcd     = blockIdx.x & 7;
    const int slot_   = blockIdx.x >> 3;
    const int bt      = xcd * 4 + (slot_ & 3);   // batch
    const int quarter = slot_ >> 2;              // which quarter of the signal
    const int lane    = t & 63;
    const int wave    = t >> 6;
    const int frame   = quarter * 6 + (wave >> 1);  // 2 waves per 2048-frame

    // ---------------- coefficient init (threads 0..191: one per pair/frame) --
    if (t < NP * NF) {
        const int p  = t / NF;
        const int fr = t % NF;
        const float* P = params + (size_t)bt * 50 * NF;
        const Aff A = biquad_affine(2 * p,     P, fr);
        const Aff B = biquad_affine(2 * p + 1, P, fr);

        // fused one-sample transition blocks: TA, X = bB (x) cA-row, TB
        float a00 = A.t00, a01 = A.t01, a10 = A.t10, a11 = A.t11;
        float x00 = B.b0 * A.c0, x01 = B.b0 * A.c1;
        float x10 = B.b1 * A.c0, x11 = B.b1 * A.c1;
        float b00 = B.t00, b01 = B.t01, b10 = B.t10, b11 = B.t11;

        // M = Tp^16 by 4 squarings: (A,X,B) -> (A^2, XA + BX, B^2)
        #pragma unroll
        for (int i = 0; i < 4; i++) {
            const float na00 = a00 * a00 + a01 * a10;
            const float na01 = a00 * a01 + a01 * a11;
            const float na10 = a10 * a00 + a11 * a10;
            const float na11 = a10 * a01 + a11 * a11;
            const float nx00 = x00 * a00 + x01 * a10 + b00 * x00 + b01 * x10;
            const float nx01 = x00 * a01 + x01 * a11 + b00 * x01 + b01 * x11;
            const float nx10 = x10 * a00 + x11 * a10 + b10 * x00 + b11 * x10;
            const float nx11 = x10 * a01 + x11 * a11 + b10 * x01 + b11 * x11;
            const float nb00 = b00 * b00 + b01 * b10;
            const float nb01 = b00 * b01 + b01 * b11;
            const float nb10 = b10 * b00 + b11 * b10;
            const float nb11 = b10 * b01 + b11 * b11;
            a00 = na00; a01 = na01; a10 = na10; a11 = na11;
            x00 = nx00; x01 = nx01; x10 = nx10; x11 = nx11;
            b00 = nb00; b01 = nb01; b10 = nb10; b11 = nb11;
        }

        float* d = sc[p][fr];
        // [0..3]  t00a t01a t10a t11a   [4..7]  b0a b1a c0a c1a
        // [8..11] c2a t00b t01b t10b    [12..15] t11b b0b b1b c0b
        // [16..19] c1b c2b M11_00 M11_01
        // [20..23] M11_10 M11_11 M21_00 M21_01
        // [24..27] M21_10 M21_11 M22_00 M22_01
        // [28..31] M22_10 M22_11 0 0
        d[0]  = A.t00; d[1]  = A.t01; d[2]  = A.t10; d[3]  = A.t11;
        d[4]  = A.b0;  d[5]  = A.b1;  d[6]  = A.c0;  d[7]  = A.c1;
        d[8]  = A.c2;  d[9]  = B.t00; d[10] = B.t01; d[11] = B.t10;
        d[12] = B.t11; d[13] = B.b0;  d[14] = B.b1;  d[15] = B.c0;
        d[16] = B.c1;  d[17] = B.c2;  d[18] = a00;   d[19] = a01;
        d[20] = a10;   d[21] = a11;   d[22] = x00;   d[23] = x01;
        d[24] = x10;   d[25] = x11;   d[26] = b00;   d[27] = b01;
        d[28] = b10;   d[29] = b11;   d[30] = 0.0f;  d[31] = 0.0f;
    }
    if (t >= 384 && t < 384 + 2 * NF) {
        const int idx = t - 384;
        const int which = idx / NF;     // 0 = in gain (row 48), 1 = out gain (row 49)
        const int fr    = idx % NF;
        const float* P = params + (size_t)bt * 50 * NF;
        const float p  = P[(48 + which) * NF + fr];
        const float db = -60.0f + 60.0f * p;
        sgain[which][fr] = __expf(db * (2.30258509f / 20.0f));
    }
    __syncthreads();

    // ---------------- load chunk (with input gain) ----------------
    FOREACH_S(DECL_S)
    {
        const float ing = sgain[0][frame];
        const float* base = audio + (size_t)bt * S
                          + (size_t)(quarter * NCH + t) * CHUNK;
        float4 q;
        q = *(const float4*)(base +  0); s00 = q.x*ing; s01 = q.y*ing; s02 = q.z*ing; s03 = q.w*ing;
        q = *(const float4*)(base +  4); s04 = q.x*ing; s05 = q.y*ing; s06 = q.z*ing; s07 = q.w*ing;
        q = *(const float4*)(base +  8); s08 = q.x*ing; s09 = q.y*ing; s10 = q.z*ing; s11 = q.w*ing;
        q = *(const float4*)(base + 12); s12 = q.x*ing; s13 = q.y*ing; s14 = q.z*ing; s15 = q.w*ing;
    }

    // ---------------- 8 cascaded fused rounds ----------------
    #pragma unroll 1
    for (int f = 0; f < NP; f++) {
        const float* d = sc[f][frame];
        const float4 q0 = *(const float4*)(d +  0);
        const float4 q1 = *(const float4*)(d +  4);
        const float4 q2 = *(const float4*)(d +  8);
        const float4 q3 = *(const float4*)(d + 12);
        const float4 q4 = *(const float4*)(d + 16);
        const float4 q5 = *(const float4*)(d + 20);
        const float4 q6 = *(const float4*)(d + 24);
        const float4 q7 = *(const float4*)(d + 28);
        const float t00a = q0.x, t01a = q0.y, t10a = q0.z, t11a = q0.w;
        const float b0a  = q1.x, b1a  = q1.y, c0a  = q1.z, c1a  = q1.w;
        const float c2a  = q2.x, t00b = q2.y, t01b = q2.z, t10b = q2.w;
        const float t11b = q3.x, b0b  = q3.y, b1b  = q3.z, c0b  = q3.w;
        const float c1b  = q4.x, c2b  = q4.y;
        // M = Tp^16 blocks (wave-uniform)
        const float M11_00 = q4.z, M11_01 = q4.w;
        const float M11_10 = q5.x, M11_11 = q5.y;
        const float M21_00 = q5.z, M21_01 = q5.w;
        const float M21_10 = q6.x, M21_11 = q6.y;
        const float M22_00 = q6.z, M22_01 = q6.w;
        const float M22_10 = q7.x, M22_11 = q7.y;

        // Phase A: zero-state run over own chunk -> affine constant (4-dim)
        float j1 = 0.0f, j2 = 0.0f, k1 = 0.0f, k2 = 0.0f;
        FOREACH_S(STEPA2)

        // constants-only Kogge-Stone on 4-dim constants; wave-uniform M^d
        // (3-block form, squared in place).
        float m11_00 = M11_00, m11_01 = M11_01, m11_10 = M11_10, m11_11 = M11_11;
        float m21_00 = M21_00, m21_01 = M21_01, m21_10 = M21_10, m21_11 = M21_11;
        float m22_00 = M22_00, m22_01 = M22_01, m22_10 = M22_10, m22_11 = M22_11;
        float Ac1 = j1, Ac2 = j2, Ac3 = k1, Ac4 = k2;
        #pragma unroll
        for (int dd = 1; dd < 64; dd <<= 1) {
            const float l1 = __shfl_up(Ac1, dd);
            const float l2 = __shfl_up(Ac2, dd);
            const float l3 = __shfl_up(Ac3, dd);
            const float l4 = __shfl_up(Ac4, dd);
            if (lane >= dd) {
                const float n1 = fmaf(m11_00, l1, fmaf(m11_01, l2, Ac1));
                const float n2 = fmaf(m11_10, l1, fmaf(m11_11, l2, Ac2));
                const float n3 = fmaf(m21_00, l1, fmaf(m21_01, l2, fmaf(m22_00, l3, fmaf(m22_01, l4, Ac3))));
                const float n4 = fmaf(m21_10, l1, fmaf(m21_11, l2, fmaf(m22_10, l3, fmaf(m22_11, l4, Ac4))));
                Ac1 = n1; Ac2 = n2; Ac3 = n3; Ac4 = n4;
            }
            // square the 3-block matrix: (A,X,B) -> (A^2, XA+BX, B^2)
            const float na00 = m11_00 * m11_00 + m11_01 * m11_10;
            const float na01 = m11_00 * m11_01 + m11_01 * m11_11;
            const float na10 = m11_10 * m11_00 + m11_11 * m11_10;
            const float na11 = m11_10 * m11_01 + m11_11 * m11_11;
            const float nx00 = m21_00 * m11_00 + m21_01 * m11_10 + m22_00 * m21_00 + m22_01 * m21_10;
            const float nx01 = m21_00 * m11_01 + m21_01 * m11_11 + m22_00 * m21_01 + m22_01 * m21_11;
            const float nx10 = m21_10 * m11_00 + m21_11 * m11_10 + m22_10 * m21_00 + m22_11 * m21_10;
            const float nx11 = m21_10 * m11_01 + m21_11 * m11_11 + m22_10 * m21_01 + m22_11 * m21_11;
            const float nb00 = m22_00 * m22_00 + m22_01 * m22_10;
            const float nb01 = m22_00 * m22_01 + m22_01 * m22_11;
            const float nb10 = m22_10 * m22_00 + m22_11 * m22_10;
            const float nb11 = m22_10 * m22_01 + m22_11 * m22_11;
            m11_00 = na00; m11_01 = na01; m11_10 = na10; m11_11 = na11;
            m21_00 = nx00; m21_01 = nx01; m21_10 = nx10; m21_11 = nx11;
            m22_00 = nb00; m22_01 = nb01; m22_10 = nb10; m22_11 = nb11;
        }
        // m = M^64 (wave aggregate); Ac at lane 63 = wave aggregate constant

        if (lane == 63) {
            float* g = sagg[wave];
            g[0]  = m11_00; g[1]  = m11_01; g[2]  = m11_10; g[3]  = m11_11;
            g[4]  = m21_00; g[5]  = m21_01; g[6]  = m21_10; g[7]  = m21_11;
            g[8]  = m22_00; g[9]  = m22_01; g[10] = m22_10; g[11] = m22_11;
            g[12] = Ac1;    g[13] = Ac2;    g[14] = Ac3;    g[15] = Ac4;
        }
        __syncthreads();

        const unsigned int tag = (unsigned int)(f + 1);
        unsigned int* stagebase = ws + ((size_t)(bt * NP + f) * NBLK) * 20;

        // Second level on wave 0: ordered KS over 12 wave aggregates.
        if (wave == 0) {
            float g11_00 = 1.0f, g11_01 = 0.0f, g11_10 = 0.0f, g11_11 = 1.0f;
            float g21_00 = 0.0f, g21_01 = 0.0f, g21_10 = 0.0f, g21_11 = 0.0f;
            float g22_00 = 1.0f, g22_01 = 0.0f, g22_10 = 0.0f, g22_11 = 1.0f;
            float gc1 = 0.0f, gc2 = 0.0f, gc3 = 0.0f, gc4 = 0.0f;
            if (lane < NWAVE) {
                const float* g = sagg[lane];
                g11_00 = g[0];  g11_01 = g[1];  g11_10 = g[2];  g11_11 = g[3];
                g21_00 = g[4];  g21_01 = g[5];  g21_10 = g[6];  g21_11 = g[7];
                g22_00 = g[8];  g22_01 = g[9];  g22_10 = g[10]; g22_11 = g[11];
                gc1 = g[12]; gc2 = g[13]; gc3 = g[14]; gc4 = g[15];
            }
            #pragma unroll
            for (int dd = 1; dd < 16; dd <<= 1) {
                const float L11_00 = __shfl_up(g11_00, dd), L11_01 = __shfl_up(g11_01, dd);
                const float L11_10 = __shfl_up(g11_10, dd), L11_11 = __shfl_up(g11_11, dd);
                const float L21_00 = __shfl_up(g21_00, dd), L21_01 = __shfl_up(g21_01, dd);
                const float L21_10 = __shfl_up(g21_10, dd), L21_11 = __shfl_up(g21_11, dd);
                const float L22_00 = __shfl_up(g22_00, dd), L22_01 = __shfl_up(g22_01, dd);
                const float L22_10 = __shfl_up(g22_10, dd), L22_11 = __shfl_up(g22_11, dd);
                const float lc1 = __shfl_up(gc1, dd), lc2 = __shfl_up(gc2, dd);
                const float lc3 = __shfl_up(gc3, dd), lc4 = __shfl_up(gc4, dd);
                if (lane >= dd && lane < NWAVE) {
                    // new = own o left : C11 = A11 L11 ; C21 = A21 L11 + A22 L21 ;
                    // C22 = A22 L22 ; c' = A lc + c
                    const float n11_00 = g11_00 * L11_00 + g11_01 * L11_10;
                    const float n11_01 = g11_00 * L11_01 + g11_01 * L11_11;
                    const float n11_10 = g11_10 * L11_00 + g11_11 * L11_10;
                    const float n11_11 = g11_10 * L11_01 + g11_11 * L11_11;
                    const float n21_00 = g21_00 * L11_00 + g21_01 * L11_10 + g22_00 * L21_00 + g22_01 * L21_10;
                    const float n21_01 = g21_00 * L11_01 + g21_01 * L11_11 + g22_00 * L21_01 + g22_01 * L21_11;
                    const float n21_10 = g21_10 * L11_00 + g21_11 * L11_10 + g22_10 * L21_00 + g22_11 * L21_10;
                    const float n21_11 = g21_10 * L11_01 + g21_11 * L11_11 + g22_10 * L21_01 + g22_11 * L21_11;
                    const float n22_00 = g22_00 * L22_00 + g22_01 * L22_10;
                    const float n22_01 = g22_00 * L22_01 + g22_01 * L22_11;
                    const float n22_10 = g22_10 * L22_00 + g22_11 * L22_10;
                    const float n22_11 = g22_10 * L22_01 + g22_11 * L22_11;
                    const float nc1 = fmaf(g11_00, lc1, fmaf(g11_01, lc2, gc1));
                    const float nc2 = fmaf(g11_10, lc1, fmaf(g11_11, lc2, gc2));
                    const float nc3 = fmaf(g21_00, lc1, fmaf(g21_01, lc2, fmaf(g22_00, lc3, fmaf(g22_01, lc4, gc3))));
                    const float nc4 = fmaf(g21_10, lc1, fmaf(g21_11, lc2, fmaf(g22_10, lc3, fmaf(g22_11, lc4, gc4))));
                    g11_00 = n11_00; g11_01 = n11_01; g11_10 = n11_10; g11_11 = n11_11;
                    g21_00 = n21_00; g21_01 = n21_01; g21_10 = n21_10; g21_11 = n21_11;
                    g22_00 = n22_00; g22_01 = n22_01; g22_10 = n22_10; g22_11 = n22_11;
                    gc1 = nc1; gc2 = nc2; gc3 = nc3; gc4 = nc4;
                }
            }

            // publish block aggregate (inclusive at lane 11) ASAP
            if (quarter < NBLK - 1 && lane == NWAVE - 1) {
                unsigned int* slot = stagebase + quarter * 20;
                float* dp = (float*)(slot + 1);
                __hip_atomic_store(&dp[0],  g11_00, __ATOMIC_RELAXED, __HIP_MEMORY_SCOPE_AGENT);
                __hip_atomic_store(&dp[1],  g11_01, __ATOMIC_RELAXED, __HIP_MEMORY_SCOPE_AGENT);
                __hip_atomic_store(&dp[2],  g11_10, __ATOMIC_RELAXED, __HIP_MEMORY_SCOPE_AGENT);
                __hip_atomic_store(&dp[3],  g11_11, __ATOMIC_RELAXED, __HIP_MEMORY_SCOPE_AGENT);
                __hip_atomic_store(&dp[4],  g21_00, __ATOMIC_RELAXED, __HIP_MEMORY_SCOPE_AGENT);
                __hip_atomic_store(&dp[5],  g21_01, __ATOMIC_RELAXED, __HIP_MEMORY_SCOPE_AGENT);
                __hip_atomic_store(&dp[6],  g21_10, __ATOMIC_RELAXED, __HIP_MEMORY_SCOPE_AGENT);
                __hip_atomic_store(&dp[7],  g21_11, __ATOMIC_RELAXED, __HIP_MEMORY_SCOPE_AGENT);
                __hip_atomic_store(&dp[8],  g22_00, __ATOMIC_RELAXED, __HIP_MEMORY_SCOPE_AGENT);
                __hip_atomic_store(&dp[9],  g22_01, __ATOMIC_RELAXED, __HIP_MEMORY_SCOPE_AGENT);
                __hip_atomic_store(&dp[10], g22_10, __ATOMIC_RELAXED, __HIP_MEMORY_SCOPE_AGENT);
                __hip_atomic_store(&dp[11], g22_11, __ATOMIC_RELAXED, __HIP_MEMORY_SCOPE_AGENT);
                __hip_atomic_store(&dp[12], gc1,    __ATOMIC_RELAXED, __HIP_MEMORY_SCOPE_AGENT);
                __hip_atomic_store(&dp[13], gc2,    __ATOMIC_RELAXED, __HIP_MEMORY_SCOPE_AGENT);
                __hip_atomic_store(&dp[14], gc3,    __ATOMIC_RELAXED, __HIP_MEMORY_SCOPE_AGENT);
                __hip_atomic_store(&dp[15], gc4,    __ATOMIC_RELAXED, __HIP_MEMORY_SCOPE_AGENT);
                __hip_atomic_store(slot, tag, __ATOMIC_RELEASE, __HIP_MEMORY_SCOPE_AGENT);
            }

            // exclusive wave prefix
            float p11_00 = __shfl_up(g11_00, 1), p11_01 = __shfl_up(g11_01, 1);
            float p11_10 = __shfl_up(g11_10, 1), p11_11 = __shfl_up(g11_11, 1);
            float p21_00 = __shfl_up(g21_00, 1), p21_01 = __shfl_up(g21_01, 1);
            float p21_10 = __shfl_up(g21_10, 1), p21_11 = __shfl_up(g21_11, 1);
            float p22_00 = __shfl_up(g22_00, 1), p22_01 = __shfl_up(g22_01, 1);
            float p22_10 = __shfl_up(g22_10, 1), p22_11 = __shfl_up(g22_11, 1);
            float pc1 = __shfl_up(gc1, 1), pc2 = __shfl_up(gc2, 1);
            float pc3 = __shfl_up(gc3, 1), pc4 = __shfl_up(gc4, 1);
            if (lane == 0) {
                p11_00 = 1.0f; p11_01 = 0.0f; p11_10 = 0.0f; p11_11 = 1.0f;
                p21_00 = 0.0f; p21_01 = 0.0f; p21_10 = 0.0f; p21_11 = 0.0f;
                p22_00 = 1.0f; p22_01 = 0.0f; p22_10 = 0.0f; p22_11 = 1.0f;
                pc1 = 0.0f; pc2 = 0.0f; pc3 = 0.0f; pc4 = 0.0f;
            }

            // lane 0: poll predecessor blocks, fold block incoming state S0
            float S1 = 0.0f, S2 = 0.0f, S3 = 0.0f, S4 = 0.0f;
            if (lane == 0 && quarter > 0) {
                float s1 = 0.0f, s2 = 0.0f, s3 = 0.0f, s4 = 0.0f;
                for (int kq = 0; kq < quarter; kq++) {
                    unsigned int* slot = stagebase + kq * 20;
                    while (__hip_atomic_load(slot, __ATOMIC_ACQUIRE, __HIP_MEMORY_SCOPE_AGENT) != tag) {
                        __builtin_amdgcn_s_sleep(1);
                    }
                    const float* dp = (const float*)(slot + 1);
                    const float a00 = __hip_atomic_load(&dp[0],  __ATOMIC_RELAXED, __HIP_MEMORY_SCOPE_AGENT);
                    const float a01 = __hip_atomic_load(&dp[1],  __ATOMIC_RELAXED, __HIP_MEMORY_SCOPE_AGENT);
                    const float a10 = __hip_atomic_load(&dp[2],  __ATOMIC_RELAXED, __HIP_MEMORY_SCOPE_AGENT);
                    const float a11 = __hip_atomic_load(&dp[3],  __ATOMIC_RELAXED, __HIP_MEMORY_SCOPE_AGENT);
                    const float x00 = __hip_atomic_load(&dp[4],  __ATOMIC_RELAXED, __HIP_MEMORY_SCOPE_AGENT);
                    const float x01 = __hip_atomic_load(&dp[5],  __ATOMIC_RELAXED, __HIP_MEMORY_SCOPE_AGENT);
                    const float x10 = __hip_atomic_load(&dp[6],  __ATOMIC_RELAXED, __HIP_MEMORY_SCOPE_AGENT);
                    const float x11 = __hip_atomic_load(&dp[7],  __ATOMIC_RELAXED, __HIP_MEMORY_SCOPE_AGENT);
                    const float e00 = __hip_atomic_load(&dp[8],  __ATOMIC_RELAXED, __HIP_MEMORY_SCOPE_AGENT);
                    const float e01 = __hip_atomic_load(&dp[9],  __ATOMIC_RELAXED, __HIP_MEMORY_SCOPE_AGENT);
                    const float e10 = __hip_atomic_load(&dp[10], __ATOMIC_RELAXED, __HIP_MEMORY_SCOPE_AGENT);
                    const float e11 = __hip_atomic_load(&dp[11], __ATOMIC_RELAXED, __HIP_MEMORY_SCOPE_AGENT);
                    const float cc1 = __hip_atomic_load(&dp[12], __ATOMIC_RELAXED, __HIP_MEMORY_SCOPE_AGENT);
                    const float cc2 = __hip_atomic_load(&dp[13], __ATOMIC_RELAXED, __HIP_MEMORY_SCOPE_AGENT);
                    const float cc3 = __hip_atomic_load(&dp[14], __ATOMIC_RELAXED, __HIP_MEMORY_SCOPE_AGENT);
                    const float cc4 = __hip_atomic_load(&dp[15], __ATOMIC_RELAXED, __HIP_MEMORY_SCOPE_AGENT);
                    const float n1 = fmaf(a00, s1, fmaf(a01, s2, cc1));
                    const float n2 = fmaf(a10, s1, fmaf(a11, s2, cc2));
                    const float n3 = fmaf(x00, s1, fmaf(x01, s2, fmaf(e00, s3, fmaf(e01, s4, cc3))));
                    const float n4 = fmaf(x10, s1, fmaf(x11, s2, fmaf(e10, s3, fmaf(e11, s4, cc4))));
                    s1 = n1; s2 = n2; s3 = n3; s4 = n4;
                }
                S1 = s1; S2 = s2; S3 = s3; S4 = s4;
            }
            S1 = __shfl(S1, 0); S2 = __shfl(S2, 0);
            S3 = __shfl(S3, 0); S4 = __shfl(S4, 0);

            // per-wave incoming state v = P(S0); lanes 0..11 write to LDS
            if (lane < NWAVE) {
                sv[lane][0] = fmaf(p11_00, S1, fmaf(p11_01, S2, pc1));
                sv[lane][1] = fmaf(p11_10, S1, fmaf(p11_11, S2, pc2));
                sv[lane][2] = fmaf(p21_00, S1, fmaf(p21_01, S2, fmaf(p22_00, S3, fmaf(p22_01, S4, pc3))));
                sv[lane][3] = fmaf(p21_10, S1, fmaf(p21_11, S2, fmaf(p22_10, S3, fmaf(p22_11, S4, pc4))));
            }
        }
        __syncthreads();

        const float vx1 = sv[wave][0];
        const float vx2 = sv[wave][1];
        const float vx3 = sv[wave][2];
        const float vx4 = sv[wave][3];

        // lane-exclusive constants
        float ce1 = __shfl_up(Ac1, 1);
        float ce2 = __shfl_up(Ac2, 1);
        float ce3 = __shfl_up(Ac3, 1);
        float ce4 = __shfl_up(Ac4, 1);
        if (lane == 0) { ce1 = 0.0f; ce2 = 0.0f; ce3 = 0.0f; ce4 = 0.0f; }

        // w = M^lane * v via in-register binary exponentiation (3-block form;
        // powers of the same M commute). 0 DS ops.
        float w1 = vx1, w2 = vx2, w3 = vx3, w4 = vx4;
        float pa00 = M11_00, pa01 = M11_01, pa10 = M11_10, pa11 = M11_11;
        float px00 = M21_00, px01 = M21_01, px10 = M21_10, px11 = M21_11;
        float pb00 = M22_00, pb01 = M22_01, pb10 = M22_10, pb11 = M22_11;
        #pragma unroll
        for (int b = 0; b < 6; b++) {
            if (lane & (1 << b)) {
                const float n1 = pa00 * w1 + pa01 * w2;
                const float n2 = pa10 * w1 + pa11 * w2;
                const float n3 = px00 * w1 + px01 * w2 + pb00 * w3 + pb01 * w4;
                const float n4 = px10 * w1 + px11 * w2 + pb10 * w3 + pb11 * w4;
                w1 = n1; w2 = n2; w3 = n3; w4 = n4;
            }
            if (b < 5) {
                const float na00 = pa00 * pa00 + pa01 * pa10;
                const float na01 = pa00 * pa01 + pa01 * pa11;
                const float na10 = pa10 * pa00 + pa11 * pa10;
                const float na11 = pa10 * pa01 + pa11 * pa11;
                const float nx00 = px00 * pa00 + px01 * pa10 + pb00 * px00 + pb01 * px10;
                const float nx01 = px00 * pa01 + px01 * pa11 + pb00 * px01 + pb01 * px11;
                const float nx10 = px10 * pa00 + px11 * pa10 + pb10 * px00 + pb11 * px10;
                const float nx11 = px10 * pa01 + px11 * pa11 + pb10 * px01 + pb11 * px11;
                const float nb00 = pb00 * pb00 + pb01 * pb10;
                const float nb01 = pb00 * pb01 + pb01 * pb11;
                const float nb10 = pb10 * pb00 + pb11 * pb10;
                const float nb11 = pb10 * pb01 + pb11 * pb11;
                pa00 = na00; pa01 = na01; pa10 = na10; pa11 = na11;
                px00 = nx00; px01 = nx01; px10 = nx10; px11 = nx11;
                pb00 = nb00; pb01 = nb01; pb10 = nb10; pb11 = nb11;
            }
        }
        j1 = w1 + ce1;
        j2 = w2 + ce2;
        k1 = w3 + ce3;
        k2 = w4 + ce4;

        // Phase C: true run from incoming state, write outputs in place
        FOREACH_S(STEPC2)
    }

    // ---------------- store (with output gain) ----------------
    {
        const float og = sgain[1][frame];
        float* base = out + (size_t)bt * S + (size_t)(quarter * NCH + t) * CHUNK;
        float4 q;
        q.x = s00*og; q.y = s01*og; q.z = s02*og; q.w = s03*og; *(float4*)(base +  0) = q;
        q.x = s04*og; q.y = s05*og; q.z = s06*og; q.w = s07*og; *(float4*)(base +  4) = q;
        q.x = s08*og; q.y = s09*og; q.z = s10*og; q.w = s11*og; *(float4*)(base +  8) = q;
        q.x = s12*og; q.y = s13*og; q.z = s14*og; q.w = s15*og; *(float4*)(base + 12) = q;
    }
}

extern "C" void kernel_launch(void* const* d_in, const int* in_sizes, int n_in,
                              void* d_out, int out_size, void* d_ws, size_t ws_size,
                              hipStream_t stream)
{
    const float* audio  = (const float*)d_in[0];
    const float* params = (const float*)d_in[1];
    float* out = (float*)d_out;
    unsigned int* ws = (unsigned int*)d_ws;
    biquad_chain_kernel<<<NBLK * NBATCH, NCH, 0, stream>>>(audio, params, out, ws);
}

// Round 6
// 147.406 us; speedup vs baseline: 1.3877x; 1.3877x over previous
//
#include <hip/hip_runtime.h>
#include <math.h>

#define NBATCH 32
#define S      49152
#define NF     24          // frames (2048 samples each)
#define NB     16          // biquads
#define CHUNK  32          // samples per lane (64 lanes x 32 = one frame)
#define NWPB   4           // waves (frames) per block
#define NBLKF  6           // blocks per batch (6 x 4 = 24 frames)
#define NCH    256         // threads per block
// R15: FRAME-PER-WAVE WAVEFRONT PIPELINE -- no block-wide combine at all.
// R9-R14 evidence: every structure where all 1536 waves rendezvous per stage
// (barrier + 12-wave KS + L2 fan) costs ~4.6k cy/stage of wall (74-99us);
// R13/R14 added register pressure and spilled (WRITE 7.4 -> 77/213MB).
// R15 changes the dependency topology: one wave owns one whole 2048-sample
// frame, so all 16 stages' inter-stage samples stay in ITS registers. The
// only cross-wave traffic is the 2-float state carry (frame fr-1 -> fr, per
// stage): write-once publish/poll, LDS within a block (4 frames), L2 across
// blocks. 2D wavefront: makespan ~ 23 hops + 16 stage-works, no barriers in
// the main loop, no second-level scan -- and the combine register footprint
// shrinks to ~12 floats, ending the spill cycle.
// Health check: WRITE_SIZE ~7.4MB / FETCH ~3.3MB (scratch shows up there).

__device__ __forceinline__ float clampf(float x, float lo, float hi) {
    return fminf(fmaxf(x, lo), hi);
}

// 32 named scalar signal registers (SSA-guaranteed; arrays spill).
#define FOREACH_S(OP) \
    OP(s00) OP(s01) OP(s02) OP(s03) OP(s04) OP(s05) OP(s06) OP(s07) \
    OP(s08) OP(s09) OP(s10) OP(s11) OP(s12) OP(s13) OP(s14) OP(s15) \
    OP(s16) OP(s17) OP(s18) OP(s19) OP(s20) OP(s21) OP(s22) OP(s23) \
    OP(s24) OP(s25) OP(s26) OP(s27) OP(s28) OP(s29) OP(s30) OP(s31)

#define DECL_S(x) float x;

// Phase A step: state only.  s' = T s + b*x
#define STEPA(x) { \
    const float n1_ = fmaf(t00, ic1, fmaf(t01, ic2, b0 * (x))); \
    const float n2_ = fmaf(t10, ic1, fmaf(t11, ic2, b1 * (x))); \
    ic1 = n1_; ic2 = n2_; }

// Phase C step: output + state.  y = c0*ic1 + c1*ic2 + c2*x, in place.
#define STEPC(x) { \
    const float y_  = fmaf(c0, ic1, fmaf(c1, ic2, c2 * (x))); \
    const float n1_ = fmaf(t00, ic1, fmaf(t01, ic2, b0 * (x))); \
    const float n2_ = fmaf(t10, ic1, fmaf(t11, ic2, b1 * (x))); \
    (x) = y_; ic1 = n1_; ic2 = n2_; }

struct Aff { float t00, t01, t10, t11, b0, b1, c0, c1, c2; };

// per-biquad affine per-sample form: s' = T s + b*x ; y = c0*s1 + c1*s2 + c2*x
__device__ __forceinline__ Aff biquad_affine(int f, const float* P, int fr) {
    const float fn = P[(3 * f + 0) * NF + fr];
    const float gn = P[(3 * f + 1) * NF + fr];
    const float qn = P[(3 * f + 2) * NF + fr];

    float Q = __expf(-0.69314718f + qn * 3.4657359f);
    Q = clampf(Q, 0.1f, 100.0f);

    float lo, hi;
    int type;                        // 0 hp, 1 lp, 2 peak, 3 lowshelf, 4 highshelf
    if      (f == 0)  { lo = 20.0f;   hi = 500.0f;   type = 0; }
    else if (f == 15) { lo = 5000.0f; hi = 20000.0f; type = 1; }
    else if (f == 1)  { lo = 50.0f;   hi = 16000.0f; type = 3; }
    else if (f == 14) { lo = 50.0f;   hi = 16000.0f; type = 4; }
    else              { lo = 100.0f;  hi = 15000.0f; type = 2; }

    const float fc = __expf(__logf(lo) + fn * (__logf(hi) - __logf(lo)));
    float g_ = __tanf((float)M_PI * fc / 96000.0f);   // angle <= 0.655 rad
    g_ = clampf(g_, 1e-6f, 100.0f);
    const float gdb = -24.0f + 48.0f * gn;

    float a1, a2, a3, m0, m1, m2;
    if (type == 0 || type == 1) {
        const float k = 1.0f / Q;
        a1 = 1.0f / (1.0f + g_ * (g_ + k)); a2 = g_ * a1; a3 = g_ * a2;
        if (type == 0) { m0 = 1.0f; m1 = -k;   m2 = -1.0f; }
        else           { m0 = 0.0f; m1 = 0.0f; m2 = 1.0f;  }
    } else if (type == 2) {
        const float A = __expf(gdb * (2.30258509f / 40.0f));
        const float k = (gdb >= 0.0f) ? 1.0f / (Q * A) : A / Q;
        a1 = 1.0f / (1.0f + g_ * (g_ + k)); a2 = g_ * a1; a3 = g_ * a2;
        m0 = 1.0f; m1 = k * (A * A - 1.0f); m2 = 0.0f;
    } else {
        const float A  = __expf(gdb * (2.30258509f / 40.0f));
        const float sA = sqrtf(A);
        const float k  = 1.0f / Q;
        float gs;
        if (type == 3) gs = (gdb >= 0.0f) ? g_ / sA : g_ * sA;
        else           gs = (gdb >= 0.0f) ? g_ * sA : g_ / sA;
        a1 = 1.0f / (1.0f + gs * (gs + k)); a2 = gs * a1; a3 = gs * a2;
        if (type == 3) { m0 = 1.0f;  m1 = k * (A - 1.0f);      m2 = A * A - 1.0f; }
        else           { m0 = A * A; m1 = k * (1.0f - A) * A;  m2 = 1.0f - A * A; }
    }

    const float q2 = a2 * a2 + a3;
    Aff r;
    r.t00 = 2.0f * a1 - 1.0f;
    r.t01 = -2.0f * a2;
    r.t10 = 2.0f * a1 * a2;
    r.t11 = 1.0f - 2.0f * q2;
    r.b0  = 2.0f * a2;
    r.b1  = 2.0f * q2;
    r.c0  = a1 * (m1 + m2 * a2);
    r.c1  = m2 * (1.0f - q2) - m1 * a2;
    r.c2  = m0 + m1 * a2 + m2 * q2;
    return r;
}

__global__ __launch_bounds__(NCH, 2)
void biquad_chain_kernel(const float* __restrict__ audio,
                         const float* __restrict__ params,
                         float* __restrict__ out,
                         unsigned int* __restrict__ ws)
{
    __shared__ float scf[NWPB][NB][16];        // per local frame, per stage: 13 floats
    __shared__ float sgain[2][NWPB];           // [0]=in gain, [1]=out gain
    __shared__ float sst[NWPB - 1][NB][2];     // intra-block state carries (write-once)
    __shared__ unsigned int stag[NWPB - 1][NB];

    const int t    = threadIdx.x;
    const int bt   = blockIdx.x & 31;          // batch; blocks of a batch stride 32
    const int blk  = blockIdx.x >> 5;          // which 4-frame group (0..5)
    const int lane = t & 63;
    const int wave = t >> 6;                   // local frame 0..3
    const int frg  = blk * NWPB + wave;        // global frame 0..23
    // XCD note: blocks {bt, bt+32, ..., bt+160} all map to XCD bt&7 under the
    // mod-8 round-robin -> the whole batch pipeline is L2-local.

    // ---------------- coefficient init (threads 0..63) ----------------
    if (t < NWPB * NB) {
        const int f   = t & 15;
        const int frl = t >> 4;
        const int fr  = blk * NWPB + frl;
        const float* P = params + (size_t)bt * 50 * NF;
        const Aff A = biquad_affine(f, P, fr);

        // M = T^32 by 5 squarings
        float u00 = A.t00, u01 = A.t01, u10 = A.t10, u11 = A.t11;
        #pragma unroll
        for (int i = 0; i < 5; i++) {
            const float n00 = u00 * u00 + u01 * u10;
            const float n01 = u00 * u01 + u01 * u11;
            const float n10 = u10 * u00 + u11 * u10;
            const float n11 = u10 * u01 + u11 * u11;
            u00 = n00; u01 = n01; u10 = n10; u11 = n11;
        }

        float* d = scf[frl][f];
        // [0-3]=t00,t01,t10,t11 [4-7]=b0,b1,c0,c1 [8-11]=c2,M00,M01,M10 [12]=M11
        d[0] = A.t00; d[1] = A.t01; d[2]  = A.t10; d[3]  = A.t11;
        d[4] = A.b0;  d[5] = A.b1;  d[6]  = A.c0;  d[7]  = A.c1;
        d[8] = A.c2;  d[9] = u00;   d[10] = u01;   d[11] = u10;
        d[12] = u11;
    }
    if (t >= 64 && t < 64 + 2 * NWPB) {
        const int idx   = t - 64;
        const int which = idx >> 2;            // 0 = in gain, 1 = out gain
        const int frl   = idx & 3;
        const int fr    = blk * NWPB + frl;
        const float* P  = params + (size_t)bt * 50 * NF;
        const float p   = P[(48 + which) * NF + fr];
        const float db  = -60.0f + 60.0f * p;
        sgain[which][frl] = __expf(db * (2.30258509f / 20.0f));
    }
    if (t < (NWPB - 1) * NB) stag[t / NB][t % NB] = 0u;
    __syncthreads();   // the ONLY barrier in the kernel

    // ---------------- load frame chunk (with input gain) ----------------
    FOREACH_S(DECL_S)
    {
        const float ing = sgain[0][wave];
        const float* base = audio + (size_t)bt * S + (size_t)frg * 2048
                          + (size_t)lane * CHUNK;
        float4 q;
        q = *(const float4*)(base +  0); s00 = q.x*ing; s01 = q.y*ing; s02 = q.z*ing; s03 = q.w*ing;
        q = *(const float4*)(base +  4); s04 = q.x*ing; s05 = q.y*ing; s06 = q.z*ing; s07 = q.w*ing;
        q = *(const float4*)(base +  8); s08 = q.x*ing; s09 = q.y*ing; s10 = q.z*ing; s11 = q.w*ing;
        q = *(const float4*)(base + 12); s12 = q.x*ing; s13 = q.y*ing; s14 = q.z*ing; s15 = q.w*ing;
        q = *(const float4*)(base + 16); s16 = q.x*ing; s17 = q.y*ing; s18 = q.z*ing; s19 = q.w*ing;
        q = *(const float4*)(base + 20); s20 = q.x*ing; s21 = q.y*ing; s22 = q.z*ing; s23 = q.w*ing;
        q = *(const float4*)(base + 24); s24 = q.x*ing; s25 = q.y*ing; s26 = q.z*ing; s27 = q.w*ing;
        q = *(const float4*)(base + 28); s28 = q.x*ing; s29 = q.y*ing; s30 = q.z*ing; s31 = q.w*ing;
    }

    // ---------------- 16 stages, wavefront-pipelined across frames --------
    #pragma unroll 1
    for (int f = 0; f < NB; f++) {
        const float* d = scf[wave][f];
        const float4 q0 = *(const float4*)(d + 0);   // t00 t01 t10 t11
        const float4 q1 = *(const float4*)(d + 4);   // b0 b1 c0 c1
        const float4 q2 = *(const float4*)(d + 8);   // c2 M00 M01 M10
        const float  M11v = d[12];
        const float t00 = q0.x, t01 = q0.y, t10 = q0.z, t11 = q0.w;
        const float b0  = q1.x, b1  = q1.y, c0  = q1.z, c1  = q1.w;
        const float c2  = q2.x;

        // Phase A: zero-state run over own chunk -> local affine constant
        float ic1 = 0.0f, ic2 = 0.0f;
        FOREACH_S(STEPA)

        // constants-only Kogge-Stone (wave-uniform M = T^32; M^d squared in
        // place). After 6 steps: Md = M^64 = T^2048 (frame aggregate).
        float Md00 = q2.y, Md01 = q2.z, Md10 = q2.w, Md11 = M11v;
        float Ac0 = ic1, Ac1 = ic2;
        #pragma unroll
        for (int dd = 1; dd < 64; dd <<= 1) {
            const float lc0 = __shfl_up(Ac0, dd);
            const float lc1 = __shfl_up(Ac1, dd);
            if (lane >= dd) {
                Ac0 = fmaf(Md00, lc0, fmaf(Md01, lc1, Ac0));
                Ac1 = fmaf(Md10, lc0, fmaf(Md11, lc1, Ac1));
            }
            const float n00 = Md00 * Md00 + Md01 * Md10;
            const float n01 = Md00 * Md01 + Md01 * Md11;
            const float n10 = Md10 * Md00 + Md11 * Md10;
            const float n11 = Md10 * Md01 + Md11 * Md11;
            Md00 = n00; Md01 = n01; Md10 = n10; Md11 = n11;
        }

        // lane-exclusive constants
        float ce0 = __shfl_up(Ac0, 1);
        float ce1 = __shfl_up(Ac1, 1);
        if (lane == 0) { ce0 = 0.0f; ce1 = 0.0f; }

        // -------- state carry: poll frame fr-1's outgoing state ------------
        const unsigned int tag = (unsigned int)(f + 1);
        float v0 = 0.0f, v1 = 0.0f;
        if (frg > 0) {
            if (wave > 0) {
                // intra-block: all lanes spin on the same LDS word (broadcast)
                while (__hip_atomic_load(&stag[wave - 1][f], __ATOMIC_ACQUIRE,
                                         __HIP_MEMORY_SCOPE_WORKGROUP) != tag)
                    __builtin_amdgcn_s_sleep(1);
                v0 = sst[wave - 1][f][0];
                v1 = sst[wave - 1][f][1];
            } else {
                // cross-block: lane 0 polls the write-once L2 slot
                unsigned int* gs = ws + ((size_t)(bt * (NBLKF - 1) + (blk - 1)) * NB + f) * 4;
                if (lane == 0) {
                    while (__hip_atomic_load(gs, __ATOMIC_ACQUIRE,
                                             __HIP_MEMORY_SCOPE_AGENT) != tag)
                        __builtin_amdgcn_s_sleep(1);
                    const float* dp = (const float*)(gs + 1);
                    v0 = __hip_atomic_load(&dp[0], __ATOMIC_RELAXED, __HIP_MEMORY_SCOPE_AGENT);
                    v1 = __hip_atomic_load(&dp[1], __ATOMIC_RELAXED, __HIP_MEMORY_SCOPE_AGENT);
                }
                v0 = __shfl(v0, 0);
                v1 = __shfl(v1, 0);
            }
        }

        // -------- publish outgoing state IMMEDIATELY (before Phase C) ------
        // outgoing = Md * v + Ac  (Ac valid at lane 63 = frame aggregate)
        if (lane == 63 && frg < NF - 1) {
            const float o0 = fmaf(Md00, v0, fmaf(Md01, v1, Ac0));
            const float o1 = fmaf(Md10, v0, fmaf(Md11, v1, Ac1));
            if (wave < NWPB - 1) {
                sst[wave][f][0] = o0;
                sst[wave][f][1] = o1;
                __hip_atomic_store(&stag[wave][f], tag, __ATOMIC_RELEASE,
                                   __HIP_MEMORY_SCOPE_WORKGROUP);
            } else {
                unsigned int* gs = ws + ((size_t)(bt * (NBLKF - 1) + blk) * NB + f) * 4;
                float* dp = (float*)(gs + 1);
                __hip_atomic_store(&dp[0], o0, __ATOMIC_RELAXED, __HIP_MEMORY_SCOPE_AGENT);
                __hip_atomic_store(&dp[1], o1, __ATOMIC_RELAXED, __HIP_MEMORY_SCOPE_AGENT);
                __hip_atomic_store(gs, tag, __ATOMIC_RELEASE, __HIP_MEMORY_SCOPE_AGENT);
            }
        }

        // -------- distribute: ic = M^lane * v + ce (binary exponentiation) -
        float w0 = v0, w1 = v1;
        float p00 = q2.y, p01 = q2.z, p10 = q2.w, p11 = M11v;
        #pragma unroll
        for (int b = 0; b < 6; b++) {
            if (lane & (1 << b)) {
                const float nw0 = fmaf(p00, w0, p01 * w1);
                const float nw1 = fmaf(p10, w0, p11 * w1);
                w0 = nw0; w1 = nw1;
            }
            if (b < 5) {
                const float n00 = p00 * p00 + p01 * p10;
                const float n01 = p00 * p01 + p01 * p11;
                const float n10 = p10 * p00 + p11 * p10;
                const float n11 = p10 * p01 + p11 * p11;
                p00 = n00; p01 = n01; p10 = n10; p11 = n11;
            }
        }
        ic1 = w0 + ce0;
        ic2 = w1 + ce1;

        // Phase C: true run from incoming state, write outputs in place
        FOREACH_S(STEPC)
    }

    // ---------------- store (with output gain) ----------------
    {
        const float og = sgain[1][wave];
        float* base = out + (size_t)bt * S + (size_t)frg * 2048
                    + (size_t)lane * CHUNK;
        float4 q;
        q.x = s00*og; q.y = s01*og; q.z = s02*og; q.w = s03*og; *(float4*)(base +  0) = q;
        q.x = s04*og; q.y = s05*og; q.z = s06*og; q.w = s07*og; *(float4*)(base +  4) = q;
        q.x = s08*og; q.y = s09*og; q.z = s10*og; q.w = s11*og; *(float4*)(base +  8) = q;
        q.x = s12*og; q.y = s13*og; q.z = s14*og; q.w = s15*og; *(float4*)(base + 12) = q;
        q.x = s16*og; q.y = s17*og; q.z = s18*og; q.w = s19*og; *(float4*)(base + 16) = q;
        q.x = s20*og; q.y = s21*og; q.z = s22*og; q.w = s23*og; *(float4*)(base + 20) = q;
        q.x = s24*og; q.y = s25*og; q.z = s26*og; q.w = s27*og; *(float4*)(base + 24) = q;
        q.x = s28*og; q.y = s29*og; q.z = s30*og; q.w = s31*og; *(float4*)(base + 28) = q;
    }
}

extern "C" void kernel_launch(void* const* d_in, const int* in_sizes, int n_in,
                              void* d_out, int out_size, void* d_ws, size_t ws_size,
                              hipStream_t stream)
{
    const float* audio  = (const float*)d_in[0];
    const float* params = (const float*)d_in[1];
    float* out = (float*)d_out;
    unsigned int* ws = (unsigned int*)d_ws;
    biquad_chain_kernel<<<NBLKF * NBATCH, NCH, 0, stream>>>(audio, params, out, ws);
}

// Round 7
// 122.399 us; speedup vs baseline: 1.6712x; 1.2043x over previous
//
#include <hip/hip_runtime.h>
#include <math.h>

#define NBATCH 32
#define S      49152
#define NF     24          // frames (2048 samples each)
#define NB     16          // biquads
#define NBLK   4           // blocks per batch (R9-proven best)
#define CHUNK  16          // samples per thread (R9-proven; 32 spills)
#define NCH    768         // threads per block
#define NWAVE  12          // waves per block
// R16: R9 skeleton + PRECOMPUTED-MATRIX combine. Evidence R9-R15: topology
// changes (spin chains, flat folds, fan scaling, wavefront) all regress or
// tie; R9's 74us = 16 rounds x ~4.6k cy. The round's serial core is wave-0's
// second level (matrix-KS ~200 inst + serial <=3-hop L2 fold) + bar2. All
// matrices there are PARAM-ONLY and every block of a batch reads the same
// params -> precompute at init, locally, in every block:
//   sMw  [f][w] : wave aggregate M_w = T_frame^1024
//   sPm  [f][w] : exclusive wave-prefix P_w = M_{w-1}...M_0
//   sWm  [f][k] : pred-quarter fold W_k = B_{q-1}...B_{k+1}
// Runtime combine carries only 2-float constants: wave-0 does a 12-step
// predicated constants-fold (no shfl, unrolled LDS loads), publishes the
// block constant (2 floats), polls pred blocks IN PARALLEL and folds with
// precomputed W_k. bar2 is replaced by a per-stage ready flag (waves proceed
// the moment sv is written); sagg is double-buffered so the single remaining
// barrier per stage is race-free. Health: WRITE ~7.4MB, VGPR <= ~80.

__device__ __forceinline__ float clampf(float x, float lo, float hi) {
    return fminf(fmaxf(x, lo), hi);
}

// 16 named scalar signal registers (SSA-guaranteed; arrays spill).
#define FOREACH_S(OP) \
    OP(s00) OP(s01) OP(s02) OP(s03) OP(s04) OP(s05) OP(s06) OP(s07) \
    OP(s08) OP(s09) OP(s10) OP(s11) OP(s12) OP(s13) OP(s14) OP(s15)

#define DECL_S(x) float x;

// Phase A step: state only.  s' = T s + b*x
#define STEPA(x) { \
    const float n1_ = fmaf(t00, ic1, fmaf(t01, ic2, b0 * (x))); \
    const float n2_ = fmaf(t10, ic1, fmaf(t11, ic2, b1 * (x))); \
    ic1 = n1_; ic2 = n2_; }

// Phase C step: output + state.  y = c0*ic1 + c1*ic2 + c2*x, in place.
#define STEPC(x) { \
    const float y_  = fmaf(c0, ic1, fmaf(c1, ic2, c2 * (x))); \
    const float n1_ = fmaf(t00, ic1, fmaf(t01, ic2, b0 * (x))); \
    const float n2_ = fmaf(t10, ic1, fmaf(t11, ic2, b1 * (x))); \
    (x) = y_; ic1 = n1_; ic2 = n2_; }

__global__ __launch_bounds__(NCH, 3)
void biquad_chain_kernel(const float* __restrict__ audio,
                         const float* __restrict__ params,
                         float* __restrict__ out,
                         unsigned int* __restrict__ ws)
{
    __shared__ float sc[NB][NF][16];      // affine(9) + T^16(4), stride 16
    __shared__ float sT2048[NB][NF][4];   // frame aggregate matrices (all frames)
    __shared__ float sMw[NB][NWAVE][4];   // wave aggregate M_w (T^1024, local)
    __shared__ float sPm[NB][NWAVE][4];   // exclusive wave-prefix P_w (local)
    __shared__ float sWm[NB][3][4];       // pred-quarter fold matrices W_k
    __shared__ float sgain[2][NF];        // [0]=in gain, [1]=out gain
    __shared__ float sagg[2][NWAVE][2];   // runtime wave constants (dbuf by stage)
    __shared__ float sv[NWAVE][2];        // per-wave incoming state
    __shared__ unsigned int sflag[NB];    // per-stage sv-ready flag

    const int t       = threadIdx.x;
    // XCD co-location swizzle (R8): all 4 quarters of a batch on one XCD.
    const int xcd     = blockIdx.x & 7;
    const int slot_   = blockIdx.x >> 3;
    const int bt      = xcd * 4 + (slot_ & 3);   // batch
    const int quarter = slot_ >> 2;              // which quarter of the signal
    const int lane    = t & 63;
    const int wave    = t >> 6;
    const int frame   = quarter * 6 + (wave >> 1);  // 2 waves per 2048-frame

    // ---------------- coefficient init (threads 0..383) ----------------
    if (t < NB * NF) {
        const int f  = t / NF;
        const int fr = t % NF;
        const float* P = params + (size_t)bt * 50 * NF;
        const float fn = P[(3 * f + 0) * NF + fr];
        const float gn = P[(3 * f + 1) * NF + fr];
        const float qn = P[(3 * f + 2) * NF + fr];

        float Q = __expf(-0.69314718f + qn * 3.4657359f);
        Q = clampf(Q, 0.1f, 100.0f);

        float lo, hi;
        int type;                        // 0 hp, 1 lp, 2 peak, 3 lowshelf, 4 highshelf
        if      (f == 0)  { lo = 20.0f;   hi = 500.0f;   type = 0; }
        else if (f == 15) { lo = 5000.0f; hi = 20000.0f; type = 1; }
        else if (f == 1)  { lo = 50.0f;   hi = 16000.0f; type = 3; }
        else if (f == 14) { lo = 50.0f;   hi = 16000.0f; type = 4; }
        else              { lo = 100.0f;  hi = 15000.0f; type = 2; }

        const float fc = __expf(__logf(lo) + fn * (__logf(hi) - __logf(lo)));
        float g_ = __tanf((float)M_PI * fc / 96000.0f);   // angle <= 0.655 rad
        g_ = clampf(g_, 1e-6f, 100.0f);
        const float gdb = -24.0f + 48.0f * gn;

        float a1, a2, a3, m0, m1, m2;
        if (type == 0 || type == 1) {
            const float k = 1.0f / Q;
            a1 = 1.0f / (1.0f + g_ * (g_ + k)); a2 = g_ * a1; a3 = g_ * a2;
            if (type == 0) { m0 = 1.0f; m1 = -k;   m2 = -1.0f; }
            else           { m0 = 0.0f; m1 = 0.0f; m2 = 1.0f;  }
        } else if (type == 2) {
            const float A = __expf(gdb * (2.30258509f / 40.0f));
            const float k = (gdb >= 0.0f) ? 1.0f / (Q * A) : A / Q;
            a1 = 1.0f / (1.0f + g_ * (g_ + k)); a2 = g_ * a1; a3 = g_ * a2;
            m0 = 1.0f; m1 = k * (A * A - 1.0f); m2 = 0.0f;
        } else {
            const float A  = __expf(gdb * (2.30258509f / 40.0f));
            const float sA = sqrtf(A);
            const float k  = 1.0f / Q;
            float gs;
            if (type == 3) gs = (gdb >= 0.0f) ? g_ / sA : g_ * sA;
            else           gs = (gdb >= 0.0f) ? g_ * sA : g_ / sA;
            a1 = 1.0f / (1.0f + gs * (gs + k)); a2 = gs * a1; a3 = gs * a2;
            if (type == 3) { m0 = 1.0f;  m1 = k * (A - 1.0f);      m2 = A * A - 1.0f; }
            else           { m0 = A * A; m1 = k * (1.0f - A) * A;  m2 = 1.0f - A * A; }
        }

        // affine per-sample form: s' = T s + b*x ; y = c0*ic1 + c1*ic2 + c2*x
        const float q2  = a2 * a2 + a3;
        const float t00 = 2.0f * a1 - 1.0f;
        const float t01 = -2.0f * a2;
        const float t10 = 2.0f * a1 * a2;
        const float t11 = 1.0f - 2.0f * q2;
        const float b0  = 2.0f * a2;
        const float b1  = 2.0f * q2;
        const float c0  = a1 * (m1 + m2 * a2);
        const float c1  = m2 * (1.0f - q2) - m1 * a2;
        const float c2  = m0 + m1 * a2 + m2 * q2;

        // T^16 by 4 squarings
        float u00 = t00, u01 = t01, u10 = t10, u11 = t11;
        #pragma unroll
        for (int i = 0; i < 4; i++) {
            const float n00 = u00 * u00 + u01 * u10;
            const float n01 = u00 * u01 + u01 * u11;
            const float n10 = u10 * u00 + u11 * u10;
            const float n11 = u10 * u01 + u11 * u11;
            u00 = n00; u01 = n01; u10 = n10; u11 = n11;
        }
        sc[f][fr][0] = t00; sc[f][fr][1] = t01; sc[f][fr][2] = t10; sc[f][fr][3] = t11;
        sc[f][fr][4] = b0;  sc[f][fr][5] = b1;  sc[f][fr][6] = c0;  sc[f][fr][7] = c1;
        sc[f][fr][8] = c2;  sc[f][fr][9] = u00; sc[f][fr][10] = u01; sc[f][fr][11] = u10;
        sc[f][fr][12] = u11;

        // continue squaring: T^16 -> T^1024 (6 more squarings)
        #pragma unroll
        for (int i = 0; i < 6; i++) {
            const float n00 = u00 * u00 + u01 * u10;
            const float n01 = u00 * u01 + u01 * u11;
            const float n10 = u10 * u00 + u11 * u10;
            const float n11 = u10 * u01 + u11 * u11;
            u00 = n00; u01 = n01; u10 = n10; u11 = n11;
        }
        const int lf = fr - quarter * 6;
        if (lf >= 0 && lf < 6) {        // wave aggregates for THIS block's frames
            sMw[f][2 * lf][0] = u00; sMw[f][2 * lf][1] = u01;
            sMw[f][2 * lf][2] = u10; sMw[f][2 * lf][3] = u11;
            sMw[f][2 * lf + 1][0] = u00; sMw[f][2 * lf + 1][1] = u01;
            sMw[f][2 * lf + 1][2] = u10; sMw[f][2 * lf + 1][3] = u11;
        }
        // one more squaring: T^2048 (frame aggregate, ALL frames)
        {
            const float n00 = u00 * u00 + u01 * u10;
            const float n01 = u00 * u01 + u01 * u11;
            const float n10 = u10 * u00 + u11 * u10;
            const float n11 = u10 * u01 + u11 * u11;
            sT2048[f][fr][0] = n00; sT2048[f][fr][1] = n01;
            sT2048[f][fr][2] = n10; sT2048[f][fr][3] = n11;
        }
    }
    if (t >= 384 && t < 384 + 2 * NF) {
        const int idx = t - 384;
        const int which = idx / NF;     // 0 = in gain (row 48), 1 = out gain (row 49)
        const int fr    = idx % NF;
        const float* P = params + (size_t)bt * 50 * NF;
        const float p  = P[(48 + which) * NF + fr];
        const float db = -60.0f + 60.0f * p;
        sgain[which][fr] = __expf(db * (2.30258509f / 20.0f));
    }
    if (t < NB) sflag[t] = 0u;
    __syncthreads();

    // ------- prefix assembly (threads 0..15, one per stage) -------
    if (t < NB) {
        const int f = t;
        // exclusive wave prefixes P_w over local frames (Q = running product)
        float q00 = 1.0f, q01 = 0.0f, q10 = 0.0f, q11 = 1.0f;
        #pragma unroll
        for (int k = 0; k < 6; k++) {
            sPm[f][2 * k][0] = q00; sPm[f][2 * k][1] = q01;
            sPm[f][2 * k][2] = q10; sPm[f][2 * k][3] = q11;
            const float m00 = sMw[f][2 * k][0], m01 = sMw[f][2 * k][1];
            const float m10 = sMw[f][2 * k][2], m11 = sMw[f][2 * k][3];
            // P_{2k+1} = T1024 * Q
            sPm[f][2 * k + 1][0] = m00 * q00 + m01 * q10;
            sPm[f][2 * k + 1][1] = m00 * q01 + m01 * q11;
            sPm[f][2 * k + 1][2] = m10 * q00 + m11 * q10;
            sPm[f][2 * k + 1][3] = m10 * q01 + m11 * q11;
            // Q = T2048[local k] * Q
            const float g00 = sT2048[f][quarter * 6 + k][0], g01 = sT2048[f][quarter * 6 + k][1];
            const float g10 = sT2048[f][quarter * 6 + k][2], g11 = sT2048[f][quarter * 6 + k][3];
            const float n00 = g00 * q00 + g01 * q10;
            const float n01 = g00 * q01 + g01 * q11;
            const float n10 = g10 * q00 + g11 * q10;
            const float n11 = g10 * q01 + g11 * q11;
            q00 = n00; q01 = n01; q10 = n10; q11 = n11;
        }
        // pred-quarter fold matrices: W_{q-1}=I ; W_k = W_{k+1} * B_{k+1}
        if (quarter > 0) {
            float r00 = 1.0f, r01 = 0.0f, r10 = 0.0f, r11 = 1.0f;
            for (int k = quarter - 1; k >= 0; k--) {
                sWm[f][k][0] = r00; sWm[f][k][1] = r01;
                sWm[f][k][2] = r10; sWm[f][k][3] = r11;
                if (k > 0) {
                    // B_k = prod over frames 6k..6k+5 of T2048 (left-multiply)
                    float b00 = 1.0f, b01 = 0.0f, b10 = 0.0f, b11 = 1.0f;
                    #pragma unroll
                    for (int m = 0; m < 6; m++) {
                        const float g00 = sT2048[f][6 * k + m][0], g01 = sT2048[f][6 * k + m][1];
                        const float g10 = sT2048[f][6 * k + m][2], g11 = sT2048[f][6 * k + m][3];
                        const float n00 = g00 * b00 + g01 * b10;
                        const float n01 = g00 * b01 + g01 * b11;
                        const float n10 = g10 * b00 + g11 * b10;
                        const float n11 = g10 * b01 + g11 * b11;
                        b00 = n00; b01 = n01; b10 = n10; b11 = n11;
                    }
                    // R = R * B_k
                    const float n00 = r00 * b00 + r01 * b10;
                    const float n01 = r00 * b01 + r01 * b11;
                    const float n10 = r10 * b00 + r11 * b10;
                    const float n11 = r10 * b01 + r11 * b11;
                    r00 = n00; r01 = n01; r10 = n10; r11 = n11;
                }
            }
        }
    }
    __syncthreads();

    // ---------------- load chunk (with input gain) ----------------
    FOREACH_S(DECL_S)
    {
        const float ing = sgain[0][frame];
        const float* base = audio + (size_t)bt * S
                          + (size_t)(quarter * NCH + t) * CHUNK;
        float4 q;
        q = *(const float4*)(base +  0); s00 = q.x*ing; s01 = q.y*ing; s02 = q.z*ing; s03 = q.w*ing;
        q = *(const float4*)(base +  4); s04 = q.x*ing; s05 = q.y*ing; s06 = q.z*ing; s07 = q.w*ing;
        q = *(const float4*)(base +  8); s08 = q.x*ing; s09 = q.y*ing; s10 = q.z*ing; s11 = q.w*ing;
        q = *(const float4*)(base + 12); s12 = q.x*ing; s13 = q.y*ing; s14 = q.z*ing; s15 = q.w*ing;
    }

    // ---------------- 16 cascaded stages ----------------
    #pragma unroll 1
    for (int f = 0; f < NB; f++) {
        const float4 q0 = *(const float4*)&sc[f][frame][0];  // t00 t01 t10 t11
        const float4 q1 = *(const float4*)&sc[f][frame][4];  // b0 b1 c0 c1
        const float4 q2 = *(const float4*)&sc[f][frame][8];  // c2 M00 M01 M10
        const float  M11v = sc[f][frame][12];
        const float t00 = q0.x, t01 = q0.y, t10 = q0.z, t11 = q0.w;
        const float b0  = q1.x, b1  = q1.y, c0  = q1.z, c1  = q1.w;
        const float c2  = q2.x;

        // Phase A: zero-state run over own chunk -> affine constant
        float ic1 = 0.0f, ic2 = 0.0f;
        FOREACH_S(STEPA)

        // constants-only Kogge-Stone: wave-uniform M = T^16, M^d squared in place
        float Md00 = q2.y, Md01 = q2.z, Md10 = q2.w, Md11 = M11v;
        float Ac0 = ic1, Ac1 = ic2;
        #pragma unroll
        for (int d = 1; d < 64; d <<= 1) {
            const float lc0 = __shfl_up(Ac0, d);
            const float lc1 = __shfl_up(Ac1, d);
            if (lane >= d) {
                Ac0 = fmaf(Md00, lc0, fmaf(Md01, lc1, Ac0));
                Ac1 = fmaf(Md10, lc0, fmaf(Md11, lc1, Ac1));
            }
            const float n00 = Md00 * Md00 + Md01 * Md10;
            const float n01 = Md00 * Md01 + Md01 * Md11;
            const float n10 = Md10 * Md00 + Md11 * Md10;
            const float n11 = Md10 * Md01 + Md11 * Md11;
            Md00 = n00; Md01 = n01; Md10 = n10; Md11 = n11;
        }
        // Ac at lane 63 = wave aggregate constant

        const int buf = f & 1;
        if (lane == 63) {
            sagg[buf][wave][0] = Ac0;
            sagg[buf][wave][1] = Ac1;
        }
        __syncthreads();   // the ONE barrier per stage (sagg[buf] ready)

        const unsigned int tag = (unsigned int)(f + 1);
        unsigned int* stagebase = ws + ((size_t)(bt * NB + f) * NBLK) * 8;

        // -------- wave 0: constants-only second level ----------------------
        if (wave == 0) {
            // predicated 12-step fold: lane w ends with exclusive prefix
            // constant Pc_w; lane 12 ends with the block-own inclusive.
            float Pc0 = 0.0f, Pc1 = 0.0f;
            #pragma unroll
            for (int j = 0; j < NWAVE; j++) {
                const float a0 = sagg[buf][j][0];
                const float a1v = sagg[buf][j][1];
                const float m00 = sMw[f][j][0], m01 = sMw[f][j][1];
                const float m10 = sMw[f][j][2], m11 = sMw[f][j][3];
                if (lane > j) {
                    const float n0 = fmaf(m00, Pc0, fmaf(m01, Pc1, a0));
                    const float n1 = fmaf(m10, Pc0, fmaf(m11, Pc1, a1v));
                    Pc0 = n0; Pc1 = n1;
                }
            }

            // publish block-own constant ASAP (no S0 dependency -> parallel
            // across quarters, consumers fold with their local W matrices)
            if (quarter < NBLK - 1 && lane == NWAVE) {
                unsigned int* slot = stagebase + quarter * 8;
                float* dp = (float*)(slot + 1);
                __hip_atomic_store(&dp[0], Pc0, __ATOMIC_RELAXED, __HIP_MEMORY_SCOPE_AGENT);
                __hip_atomic_store(&dp[1], Pc1, __ATOMIC_RELAXED, __HIP_MEMORY_SCOPE_AGENT);
                __hip_atomic_store(slot, tag, __ATOMIC_RELEASE, __HIP_MEMORY_SCOPE_AGENT);
            }

            // block incoming state: PARALLEL polls + precomputed-W fold
            float S0x = 0.0f, S0y = 0.0f;
            if (quarter > 0) {
                float ux = 0.0f, uy = 0.0f;
                if (lane < quarter) {
                    unsigned int* slot = stagebase + lane * 8;
                    while (__hip_atomic_load(slot, __ATOMIC_ACQUIRE, __HIP_MEMORY_SCOPE_AGENT) != tag) {
                        __builtin_amdgcn_s_sleep(1);
                    }
                    const float* dp = (const float*)(slot + 1);
                    const float cx = __hip_atomic_load(&dp[0], __ATOMIC_RELAXED, __HIP_MEMORY_SCOPE_AGENT);
                    const float cy = __hip_atomic_load(&dp[1], __ATOMIC_RELAXED, __HIP_MEMORY_SCOPE_AGENT);
                    const float w00 = sWm[f][lane][0], w01 = sWm[f][lane][1];
                    const float w10 = sWm[f][lane][2], w11 = sWm[f][lane][3];
                    ux = fmaf(w00, cx, w01 * cy);
                    uy = fmaf(w10, cx, w11 * cy);
                }
                S0x = __shfl(ux, 0);
                S0y = __shfl(uy, 0);
                if (quarter > 1) { S0x += __shfl(ux, 1); S0y += __shfl(uy, 1); }
                if (quarter > 2) { S0x += __shfl(ux, 2); S0y += __shfl(uy, 2); }
            }

            // per-wave incoming state v = P_w * S0 + Pc_w ; lanes 0..11
            if (lane < NWAVE) {
                const float p00 = sPm[f][lane][0], p01 = sPm[f][lane][1];
                const float p10 = sPm[f][lane][2], p11 = sPm[f][lane][3];
                sv[lane][0] = fmaf(p00, S0x, fmaf(p01, S0y, Pc0));
                sv[lane][1] = fmaf(p10, S0x, fmaf(p11, S0y, Pc1));
            }
            if (lane == 0) {
                __hip_atomic_store(&sflag[f], tag, __ATOMIC_RELEASE,
                                   __HIP_MEMORY_SCOPE_WORKGROUP);
            }
        } else {
            // ready-flag spin replaces bar2: proceed the moment sv is written
            while (__hip_atomic_load(&sflag[f], __ATOMIC_ACQUIRE,
                                     __HIP_MEMORY_SCOPE_WORKGROUP) != tag)
                __builtin_amdgcn_s_sleep(1);
        }

        const float vx = sv[wave][0];
        const float vy = sv[wave][1];

        // lane-exclusive constants
        float ce0 = __shfl_up(Ac0, 1);
        float ce1 = __shfl_up(Ac1, 1);
        if (lane == 0) { ce0 = 0.0f; ce1 = 0.0f; }

        // w = M^lane * v via in-register binary exponentiation. 0 DS ops.
        float w0 = vx, w1 = vy;
        float p00 = q2.y, p01 = q2.z, p10 = q2.w, p11 = M11v;
        #pragma unroll
        for (int b = 0; b < 6; b++) {
            if (lane & (1 << b)) {
                const float nw0 = fmaf(p00, w0, p01 * w1);
                const float nw1 = fmaf(p10, w0, p11 * w1);
                w0 = nw0; w1 = nw1;
            }
            if (b < 5) {
                const float n00 = p00 * p00 + p01 * p10;
                const float n01 = p00 * p01 + p01 * p11;
                const float n10 = p10 * p00 + p11 * p10;
                const float n11 = p10 * p01 + p11 * p11;
                p00 = n00; p01 = n01; p10 = n10; p11 = n11;
            }
        }
        ic1 = w0 + ce0;
        ic2 = w1 + ce1;

        // Phase C: true run from incoming state, write outputs in place
        FOREACH_S(STEPC)
    }

    // ---------------- store (with output gain) ----------------
    {
        const float og = sgain[1][frame];
        float* base = out + (size_t)bt * S + (size_t)(quarter * NCH + t) * CHUNK;
        float4 q;
        q.x = s00*og; q.y = s01*og; q.z = s02*og; q.w = s03*og; *(float4*)(base +  0) = q;
        q.x = s04*og; q.y = s05*og; q.z = s06*og; q.w = s07*og; *(float4*)(base +  4) = q;
        q.x = s08*og; q.y = s09*og; q.z = s10*og; q.w = s11*og; *(float4*)(base +  8) = q;
        q.x = s12*og; q.y = s13*og; q.z = s14*og; q.w = s15*og; *(float4*)(base + 12) = q;
    }
}

extern "C" void kernel_launch(void* const* d_in, const int* in_sizes, int n_in,
                              void* d_out, int out_size, void* d_ws, size_t ws_size,
                              hipStream_t stream)
{
    const float* audio  = (const float*)d_in[0];
    const float* params = (const float*)d_in[1];
    float* out = (float*)d_out;
    unsigned int* ws = (unsigned int*)d_ws;
    biquad_chain_kernel<<<NBLK * NBATCH, NCH, 0, stream>>>(audio, params, out, ws);
}